// Round 6
// baseline (651.536 us; speedup 1.0000x reference)
//
#include <hip/hip_runtime.h>
#include <hip/hip_fp16.h>
#include <math.h>

#define HH    1024
#define WWID  1024
#define WR    513
#define NIMG  96
#define NGRP  65
#define KSEG  17
#define FEAT  256
#define FIN   144

typedef _Float16 half8_t __attribute__((ext_vector_type(8)));
typedef float f32x4 __attribute__((ext_vector_type(4)));

__device__ __forceinline__ f32x4 mfma16(half8_t a, half8_t b, f32x4 c) {
    return __builtin_amdgcn_mfma_f32_16x16x32_f16(a, b, c, 0, 0, 0);
}

__device__ __forceinline__ float2 cmul(float2 a, float2 b) {
    return make_float2(a.x * b.x - a.y * b.y, a.x * b.y + a.y * b.x);
}

// exact reference binning (16 compares) — used by k_counts
__device__ __forceinline__ int radial_bin(int hf, int k) {
    const float maxr = 0.707106781186547524f;
    float v = (float)(hf < 512 ? hf : hf - 1024) * (1.0f / 1024.0f);
    float u = (float)k * (1.0f / 1024.0f);
    float rad = sqrtf(u * u + v * v);
    int bin = 0;
#pragma unroll
    for (int l = 1; l <= 16; ++l) {
        float lower = (maxr * (float)l) * 0.0625f;
        bin += (rad >= lower) ? 1 : 0;
    }
    return bin;
}

// fast bin: candidate from one multiply, then EXACT boundary checks (same arithmetic
// as reference). Candidate provably within +-1 -> single adjust suffices.
__device__ __forceinline__ int fast_bin(float rad) {
    int c = (int)(rad * 22.62741699796952f);
    if (c > 16) c = 16;
    if (c < 16 && rad >= (0.707106781186547524f * (float)(c + 1)) * 0.0625f) c++;
    else if (rad < (0.707106781186547524f * (float)c) * 0.0625f) c--;
    return c;
}

// ---- register-resident 1024-pt FFT pieces (verified r3-r5) --------------------------
// Steps A+B: input a[BR4[j]] = x[l + 64j]; after call a[r] = V[n1=l][k2=r]
// (16-pt DIT over regs, natural k2 order, then twiddle W_1024^{l*r}).
// Returns u16 = w1^16 for Step C.
__device__ __forceinline__ float2 wave_fft_AB(float2 a[16], int l) {
    constexpr float TW16C[8] = {1.f, 0.9238795325112867f, 0.7071067811865476f,
                                0.3826834323650898f, 0.f, -0.3826834323650898f,
                                -0.7071067811865476f, -0.9238795325112867f};
    constexpr float TW16S[8] = {0.f, -0.3826834323650898f, -0.7071067811865476f,
                                -0.9238795325112867f, -1.f, -0.9238795325112867f,
                                -0.7071067811865476f, -0.3826834323650898f};
#pragma unroll
    for (int m = 2; m <= 16; m <<= 1) {
        const int half = m >> 1;
        const int tstep = 16 / m;
#pragma unroll
        for (int bse = 0; bse < 16; bse += m) {
#pragma unroll
            for (int jj = 0; jj < 8; ++jj) {
                if (jj < half) {
                    float2 w = make_float2(TW16C[jj * tstep], TW16S[jj * tstep]);
                    float2 tv = cmul(a[bse + half + jj], w);
                    float2 u0 = a[bse + jj];
                    a[bse + jj]        = make_float2(u0.x + tv.x, u0.y + tv.y);
                    a[bse + half + jj] = make_float2(u0.x - tv.x, u0.y - tv.y);
                }
            }
        }
    }
    float sn, cs;
    sincosf((float)l * (-6.28318530717958647692f / 1024.0f), &sn, &cs);
    float2 w1 = make_float2(cs, sn);
    float2 wr = w1;
    a[1] = cmul(a[1], w1);
#pragma unroll
    for (int r = 2; r < 16; ++r) {
        wr = cmul(wr, w1);
        a[r] = cmul(a[r], wr);
    }
    return cmul(wr, w1); // w1^16
}

// Step C (shuffle version, used by k_rowfft): 64-pt DIF across lanes.
// Output: lane p, reg r <-> X[16*bitrev6(p) + r].
__device__ __forceinline__ void wave_fft_C(float2 a[16], int l, float2 u) {
#pragma unroll
    for (int half = 32; half >= 1; half >>= 1) {
        float2 tw = make_float2(-u.x, -u.y);
        bool up = (l & half) != 0;
#pragma unroll
        for (int r = 0; r < 16; ++r) {
            float ox = __shfl_xor(a[r].x, half);
            float oy = __shfl_xor(a[r].y, half);
            float2 s = up ? make_float2(ox - a[r].x, oy - a[r].y)
                          : make_float2(a[r].x + ox, a[r].y + oy);
            a[r] = up ? cmul(s, tw) : s;
        }
        if (half > 1) u = cmul(u, u);
    }
}

static __device__ __constant__ int BR4[16] = {0,8,4,12,2,10,6,14,1,9,5,13,3,11,7,15};

// ---------------- W64 MFMA fragment table: frag f = reim*8 + kt*4 + nt ---------------
// wtab[(f*64 + l)*8 + j] = {cos,sin}(-2*pi*(n1*k1 mod 64)/64), n1 = kt*32+(l>>4)*8+j,
// k1 = nt*16 + (l&15).  (B-operand layout of mfma_f32_16x16x32_f16.)
__global__ __launch_bounds__(256) void k_wtab(__half* __restrict__ wtab) {
    int i = blockIdx.x * 256 + threadIdx.x;
    if (i >= 16 * 64 * 8) return;
    int f = i >> 9;
    int l = (i >> 3) & 63;
    int j = i & 7;
    int reim = f >> 3, kt = (f >> 2) & 1, nt = f & 3;
    int n1 = kt * 32 + ((l >> 4) << 3) + j;
    int k1 = nt * 16 + (l & 15);
    float ang = -6.28318530717958647692f * (float)((n1 * k1) & 63) * (1.0f / 64.0f);
    float v = reim ? sinf(ang) : cosf(ang);
    wtab[i] = __float2half(v);
}

// ---------------- Kernel 1: row FFTs (verified r5, unchanged) ------------------------
__global__ __launch_bounds__(512) void k_rowfft(const float* __restrict__ x,
                                                __half2* __restrict__ interm,
                                                int img0) {
    __shared__ __half2 tile[WR][17];
    const int t = threadIdx.x;
    const int w = t >> 6;
    const int l = t & 63;
    const int blk = blockIdx.x;
    const int iy = blockIdx.y;
    const int img = img0 + iy;
    const int h0 = blk * 16;
    const int h1 = h0 + 2 * w, h2 = h1 + 1;

    const float* r1 = x + ((size_t)img * HH + h1) * WWID;
    const float* r2 = x + ((size_t)img * HH + h2) * WWID;
    float2 a[16];
#pragma unroll
    for (int j = 0; j < 16; ++j) {
        int i = l + 64 * j;
        a[BR4[j]] = make_float2(r1[i], r2[i]);
    }

    float2 u16 = wave_fft_AB(a, l);
    wave_fft_C(a, l, u16);

    const int b = (int)(__brev((unsigned)l) >> 26);
#pragma unroll
    for (int r = 0; r < 16; ++r) {
        float2 znr;
        if (r == 0) {
            int cblk = (64 - b) & 63;
            int q = (int)(__brev((unsigned)cblk) >> 26);
            znr.x = __shfl(a[0].x, q);
            znr.y = __shfl(a[0].y, q);
        } else {
            znr.x = __shfl_xor(a[16 - r].x, 63);
            znr.y = __shfl_xor(a[16 - r].y, 63);
        }
        int k = 16 * b + r;
        if (k <= 512) {
            int cc = b & 15;
            tile[k][(2 * w) ^ cc] =
                __floats2half2_rn(0.5f * (a[r].x + znr.x), 0.5f * (a[r].y - znr.y));
            tile[k][(2 * w + 1) ^ cc] =
                __floats2half2_rn(0.5f * (a[r].y + znr.y), 0.5f * (znr.x - a[r].x));
        }
    }
    __syncthreads();

    __half2* gout = interm + (size_t)iy * WR * HH + h0;
    for (int idx = t; idx < WR * 16; idx += 512) {
        int k = idx >> 4;
        int hh = idx & 15;
        gout[(size_t)k * HH + hh] = tile[k][hh ^ ((k >> 4) & 15)];
    }
}

// ------------- Kernel 2: column FFTs — Steps A/B in registers, Step C via MFMA -------
__global__ __launch_bounds__(512) void k_colfft(const __half2* __restrict__ interm,
                                                const uint4* __restrict__ wtabg,
                                                float* __restrict__ partials,
                                                int img0) {
    __shared__ uint4 wtabs[16 * 64];           // 16 KB W64 fragment table
    __shared__ __half2 vlds[8][64][17];        // per-wave V redistribution (pad 17)
    __shared__ float wsum[8][KSEG][8][2];      // 8 spread slots vs atomic serialization
    __shared__ unsigned wmax8[8][KSEG][8];
    const int t = threadIdx.x;
    const int g = blockIdx.x;
    const int iy = blockIdx.y;
    const int img = img0 + iy;
    const int wv = t >> 6;
    const int l = t & 63;
    const int k = g * 8 + wv;

    // stage W table + zero accumulators
    wtabs[t] = wtabg[t];
    wtabs[t + 512] = wtabg[t + 512];
    for (int i = t; i < 8 * KSEG * 8; i += 512) {
        int w = i / (KSEG * 8);
        int rem = i - w * (KSEG * 8);
        int bb = rem >> 3, sl = rem & 7;
        wsum[w][bb][sl][0] = 0.f;
        wsum[w][bb][sl][1] = 0.f;
        wmax8[w][bb][sl] = 0u;
    }
    __syncthreads();

    if (k <= 512) {   // wave-uniform
        const __half2* gcol = interm + (size_t)iy * WR * HH + (size_t)k * HH;
        float2 a[16];
#pragma unroll
        for (int j = 0; j < 16; ++j)
            a[BR4[j]] = __half22float2(gcol[l + 64 * j]);

        wave_fft_AB(a, l);    // a[r] = V[n1=l][k2=r]

        // redistribute V through per-wave LDS (write [lane][reg], read fragments)
#pragma unroll
        for (int r = 0; r < 16; ++r)
            vlds[wv][l][r] = __floats2half2_rn(a[r].x, a[r].y);

        f32x4 accBr[4], accBi[4];
#pragma unroll
        for (int nt = 0; nt < 4; ++nt) {
            accBr[nt] = (f32x4){0.f, 0.f, 0.f, 0.f};
            accBi[nt] = (f32x4){0.f, 0.f, 0.f, 0.f};
        }

#pragma unroll
        for (int kt = 0; kt < 2; ++kt) {
            unsigned u[8];
#pragma unroll
            for (int j = 0; j < 8; ++j) {
                int n1 = kt * 32 + ((l >> 4) << 3) + j;
                __half2 hv = vlds[wv][n1][l & 15];
                u[j] = *reinterpret_cast<unsigned*>(&hv);
            }
            union U8 { unsigned u[4]; half8_t h; uint4 q; };
            U8 vr, vi, mvi;
#pragma unroll
            for (int p = 0; p < 4; ++p) {
                vr.u[p]  = (u[2 * p] & 0xffffu) | (u[2 * p + 1] << 16);
                vi.u[p]  = (u[2 * p] >> 16) | (u[2 * p + 1] & 0xffff0000u);
                mvi.u[p] = vi.u[p] ^ 0x80008000u;
            }
#pragma unroll
            for (int nt = 0; nt < 4; ++nt) {
                U8 wc, ws;
                wc.q = wtabs[(0 + kt * 4 + nt) * 64 + l];   // cos frags
                ws.q = wtabs[(8 + kt * 4 + nt) * 64 + l];   // sin frags
                accBr[nt] = mfma16(vr.h, wc.h, accBr[nt]);
                accBr[nt] = mfma16(mvi.h, ws.h, accBr[nt]);
                accBi[nt] = mfma16(vr.h, ws.h, accBi[nt]);
                accBi[nt] = mfma16(vi.h, wc.h, accBi[nt]);
            }
        }

        // stats: lane holds h = (l>>4)*4+q + 16*(l&15) + 256*nt  (4 runs of 4 rows;
        // runs never straddle h=512 since hbase%4==0; <=1 bin boundary per run)
        const float uf = (float)k * (1.0f / 1024.0f);
        const float uu = uf * uf;
        const int slot = (((l >> 4) << 1) | (l & 1));
#pragma unroll
        for (int nt = 0; nt < 4; ++nt) {
            int hbase = ((l >> 4) << 2) + ((l & 15) << 4) + (nt << 8);
            float vf0 = (float)(hbase < 512 ? hbase : hbase - 1024) * (1.0f / 1024.0f);
            float rad0 = sqrtf(fmaf(vf0, vf0, uu));
            int h3 = hbase + 3;
            float vf3 = (float)(h3 < 512 ? h3 : h3 - 1024) * (1.0f / 1024.0f);
            float rad3 = sqrtf(fmaf(vf3, vf3, uu));
            int binF = fast_bin(rad0);
            int binL = fast_bin(rad3);
            int bHi = (binF > binL) ? binF : binL;
            float Lmid = (0.707106781186547524f * (float)bHi) * 0.0625f;

            float sA1 = 0.f, sA2 = 0.f, mA = 0.f;
            float sB1 = 0.f, sB2 = 0.f, mB = 0.f;
#pragma unroll
            for (int q = 0; q < 4; ++q) {
                int h = hbase + q;
                float vf = (float)(h < 512 ? h : h - 1024) * (1.0f / 1024.0f);
                float rad = sqrtf(fmaf(vf, vf, uu));
                float br = accBr[nt][q], bi = accBi[nt][q];
                float m = sqrtf(fmaf(br, br, bi * bi)) * (1.0f / 1024.0f);
                bool c = (rad >= Lmid);
                float mAs = c ? m : 0.f;
                float mBs = c ? 0.f : m;
                sA1 += mAs; sA2 = fmaf(mAs, m, sA2); mA = fmaxf(mA, mAs);
                sB1 += mBs; sB2 = fmaf(mBs, m, sB2); mB = fmaxf(mB, mBs);
            }
            atomicAdd(&wsum[wv][bHi][slot][0], sA1);
            atomicAdd(&wsum[wv][bHi][slot][1], sA2);
            atomicMax(&wmax8[wv][bHi][slot], __float_as_uint(mA));
            if (bHi > 0) {
                atomicAdd(&wsum[wv][bHi - 1][slot][0], sB1);
                atomicAdd(&wsum[wv][bHi - 1][slot][1], sB2);
                atomicMax(&wmax8[wv][bHi - 1][slot], __float_as_uint(mB));
            }
        }
    }
    __syncthreads();

    if (t < KSEG) {
        float aS = 0.f, bS = 0.f, cM = 0.f;
#pragma unroll
        for (int w = 0; w < 8; ++w)
#pragma unroll
            for (int sl = 0; sl < 8; ++sl) {
                aS += wsum[w][t][sl][0];
                bS += wsum[w][t][sl][1];
                cM = fmaxf(cM, __uint_as_float(wmax8[w][t][sl]));
            }
        float* dstp = partials + ((size_t)img * NGRP + g) * (KSEG * 3) + t * 3;
        dstp[0] = aS; dstp[1] = bS; dstp[2] = cM;
    }
}

// ---------------- counts (exact reference binning, deterministic) --------------------
__global__ __launch_bounds__(256) void k_counts(unsigned* __restrict__ counts) {
    int cnt[KSEG];
#pragma unroll
    for (int l = 0; l < KSEG; ++l) cnt[l] = 0;
    const int total = HH * WR;
    for (int idx = blockIdx.x * 256 + threadIdx.x; idx < total; idx += gridDim.x * 256) {
        int h = idx / WR;
        int k = idx - h * WR;
        int bin = radial_bin(h, k);
#pragma unroll
        for (int l = 0; l < KSEG; ++l) cnt[l] += (bin == l) ? 1 : 0;
    }
    const int lane = threadIdx.x & 63;
#pragma unroll
    for (int l = 0; l < KSEG; ++l) {
        int c = cnt[l];
        for (int off = 32; off > 0; off >>= 1) c += __shfl_xor(c, off);
        if (lane == 0 && c > 0) atomicAdd(&counts[l], (unsigned)c);
    }
}

// ---------------- Kernel 3: finalize stats + MLP + LayerNorm -------------------------
__global__ __launch_bounds__(256) void k_mlp(const float* __restrict__ partials,
                                             const unsigned* __restrict__ counts,
                                             const float* __restrict__ W1,
                                             const float* __restrict__ b1,
                                             const float* __restrict__ W2,
                                             const float* __restrict__ b2,
                                             const float* __restrict__ gamma,
                                             const float* __restrict__ beta,
                                             float* __restrict__ out) {
    __shared__ float feat[FIN];
    __shared__ float h1s[FEAT];
    __shared__ float red[FEAT];
    const int b = blockIdx.x;
    const int t = threadIdx.x;
    if (t < 48) {
        int c = t / 16;
        int bin = t % 16;
        const float* p = partials + ((size_t)(b * 3 + c) * NGRP) * (KSEG * 3) + bin * 3;
        float s1 = 0.f, s2 = 0.f, mxv = 0.f;
        for (int gg = 0; gg < NGRP; ++gg) {
            s1 += p[gg * (KSEG * 3) + 0];
            s2 += p[gg * (KSEG * 3) + 1];
            mxv = fmaxf(mxv, p[gg * (KSEG * 3) + 2]);
        }
        float cntf = (float)counts[bin];
        float denom = cntf + 1e-8f;
        float mean = s1 / denom;
        float var = (s2 - 2.0f * mean * s1 + cntf * mean * mean) / denom;
        var = fmaxf(var, 0.0f);
        float sd = sqrtf(var);
        mxv = fmaxf(mxv, 0.0f);
        feat[bin * 9 + 0 + c] = mean;
        feat[bin * 9 + 3 + c] = mxv;
        feat[bin * 9 + 6 + c] = sd;
    }
    __syncthreads();

    float acc = b1[t];
    for (int i = 0; i < FIN; ++i) acc += feat[i] * W1[i * FEAT + t];
    acc = (acc >= 0.0f) ? acc : 0.2f * acc;
    h1s[t] = acc;
    __syncthreads();

    float acc2 = b2[t];
    for (int i = 0; i < FEAT; ++i) acc2 += h1s[i] * W2[i * FEAT + t];

    red[t] = acc2;
    __syncthreads();
    for (int off = 128; off > 0; off >>= 1) {
        if (t < off) red[t] += red[t + off];
        __syncthreads();
    }
    float mu = red[0] * (1.0f / 256.0f);
    __syncthreads();
    float dvt = acc2 - mu;
    red[t] = dvt * dvt;
    __syncthreads();
    for (int off = 128; off > 0; off >>= 1) {
        if (t < off) red[t] += red[t + off];
        __syncthreads();
    }
    float va = red[0] * (1.0f / 256.0f);
    out[(size_t)b * FEAT + t] = dvt / sqrtf(va + 1e-5f) * gamma[t] + beta[t];
}

// --------------------------------------------------------------------------------------
extern "C" void kernel_launch(void* const* d_in, const int* in_sizes, int n_in,
                              void* d_out, int out_size, void* d_ws, size_t ws_size,
                              hipStream_t stream) {
    const float* x     = (const float*)d_in[0];
    const float* W1    = (const float*)d_in[1];
    const float* b1    = (const float*)d_in[2];
    const float* W2    = (const float*)d_in[3];
    const float* b2    = (const float*)d_in[4];
    const float* gamma = (const float*)d_in[5];
    const float* beta  = (const float*)d_in[6];
    float* out = (float*)d_out;

    char* ws = (char*)d_ws;
    unsigned* counts = (unsigned*)ws;
    float* partials = (float*)(ws + 256);
    const size_t partialsBytes = (size_t)NIMG * NGRP * KSEG * 3 * sizeof(float);
    const size_t wtabOff = (256 + partialsBytes + 255) & ~(size_t)255;
    __half* wtab = (__half*)(ws + wtabOff);
    const size_t intermOff = (wtabOff + 16384 + 255) & ~(size_t)255;
    __half2* interm = (__half2*)(ws + intermOff);
    const size_t perImg = (size_t)WR * HH * sizeof(__half2);

    long long avail = (long long)ws_size - (long long)intermOff;
    int chunk = (avail > 0) ? (int)(avail / (long long)perImg) : 0;
    if (chunk > NIMG) chunk = NIMG;
    if (chunk < 1) chunk = 1;

    hipMemsetAsync(counts, 0, KSEG * sizeof(unsigned), stream);
    k_wtab<<<dim3(32), dim3(256), 0, stream>>>(wtab);
    k_counts<<<dim3(128), dim3(256), 0, stream>>>(counts);

    for (int img0 = 0; img0 < NIMG; img0 += chunk) {
        int n = NIMG - img0;
        if (n > chunk) n = chunk;
        k_rowfft<<<dim3(64, n), dim3(512), 0, stream>>>(x, interm, img0);
        k_colfft<<<dim3(NGRP, n), dim3(512), 0, stream>>>(interm, (const uint4*)wtab,
                                                          partials, img0);
    }

    k_mlp<<<dim3(32), dim3(256), 0, stream>>>(partials, counts, W1, b1, W2, b2,
                                              gamma, beta, out);
}

// Round 7
// 466.374 us; speedup vs baseline: 1.3970x; 1.3970x over previous
//
#include <hip/hip_runtime.h>
#include <hip/hip_fp16.h>
#include <math.h>

#define HH    1024
#define WWID  1024
#define WR    513
#define NIMG  96
#define NGRP  65
#define KSEG  17
#define FEAT  256
#define FIN   144

__device__ __forceinline__ float2 cmul(float2 a, float2 b) {
    return make_float2(a.x * b.x - a.y * b.y, a.x * b.y + a.y * b.x);
}

// exact reference binning (16 compares + sqrt) — used by k_counts
__device__ __forceinline__ int radial_bin(int hf, int k) {
    const float maxr = 0.707106781186547524f;
    float v = (float)(hf < 512 ? hf : hf - 1024) * (1.0f / 1024.0f);
    float u = (float)k * (1.0f / 1024.0f);
    float rad = sqrtf(u * u + v * v);
    int bin = 0;
#pragma unroll
    for (int l = 1; l <= 16; ++l) {
        float lower = (maxr * (float)l) * 0.0625f;
        bin += (rad >= lower) ? 1 : 0;
    }
    return bin;
}

// fast bin with exact boundary adjust (validated r6)
__device__ __forceinline__ int fast_bin(float rad) {
    int c = (int)(rad * 22.62741699796952f);
    if (c > 16) c = 16;
    if (c < 16 && rad >= (0.707106781186547524f * (float)(c + 1)) * 0.0625f) c++;
    else if (rad < (0.707106781186547524f * (float)c) * 0.0625f) c--;
    return c;
}

// ---- register-resident 1024-pt FFT per wave (structure verified r3-r5) --------------
// Steps A+B: input a[BR4[j]] = x[l + 64j]; after call a[r] = V[n1=l][k2=r].
// Returns w1^16 for Step C.
__device__ __forceinline__ float2 wave_fft_AB(float2 a[16], int l) {
    constexpr float TW16C[8] = {1.f, 0.9238795325112867f, 0.7071067811865476f,
                                0.3826834323650898f, 0.f, -0.3826834323650898f,
                                -0.7071067811865476f, -0.9238795325112867f};
    constexpr float TW16S[8] = {0.f, -0.3826834323650898f, -0.7071067811865476f,
                                -0.9238795325112867f, -1.f, -0.9238795325112867f,
                                -0.7071067811865476f, -0.3826834323650898f};
#pragma unroll
    for (int m = 2; m <= 16; m <<= 1) {
        const int half = m >> 1;
        const int tstep = 16 / m;
#pragma unroll
        for (int bse = 0; bse < 16; bse += m) {
#pragma unroll
            for (int jj = 0; jj < 8; ++jj) {
                if (jj < half) {
                    float2 w = make_float2(TW16C[jj * tstep], TW16S[jj * tstep]);
                    float2 tv = cmul(a[bse + half + jj], w);
                    float2 u0 = a[bse + jj];
                    a[bse + jj]        = make_float2(u0.x + tv.x, u0.y + tv.y);
                    a[bse + half + jj] = make_float2(u0.x - tv.x, u0.y - tv.y);
                }
            }
        }
    }
    // Step B: two-level twiddle products (shallow dependency tree)
    float sn, cs;
    sincosf((float)l * (-6.28318530717958647692f / 1024.0f), &sn, &cs);
    float2 w1 = make_float2(cs, sn);
    float2 w2 = cmul(w1, w1);
    float2 w3 = cmul(w2, w1);
    float2 w4 = cmul(w2, w2);
    float2 w8 = cmul(w4, w4);
    float2 w12 = cmul(w8, w4);
    a[1] = cmul(a[1], w1);
    a[2] = cmul(a[2], w2);
    a[3] = cmul(a[3], w3);
#pragma unroll
    for (int r = 4; r < 16; ++r) {
        float2 hi = (r >> 2) == 1 ? w4 : ((r >> 2) == 2 ? w8 : w12);
        float2 p = cmul(a[r], hi);
        int lo = r & 3;
        if (lo == 1) p = cmul(p, w1);
        else if (lo == 2) p = cmul(p, w2);
        else if (lo == 3) p = cmul(p, w3);
        a[r] = p;
    }
    return cmul(w8, w8); // w1^16
}

// Step C: 64-pt DIF across lanes, fma-form butterfly + unconditional twiddle.
// Output: lane p, reg r <-> X[16*bitrev6(p) + r].
__device__ __forceinline__ void wave_fft_C(float2 a[16], int l, float2 u) {
#pragma unroll
    for (int half = 32; half >= 1; half >>= 1) {
        const bool up = (l & half) != 0;
        const float sgn = up ? -1.0f : 1.0f;
        const float twx = up ? -u.x : 1.0f;   // down lanes: identity twiddle
        const float twy = up ? -u.y : 0.0f;
#pragma unroll
        for (int r = 0; r < 16; ++r) {
            float ox = __shfl_xor(a[r].x, half);
            float oy = __shfl_xor(a[r].y, half);
            float sx = fmaf(sgn, a[r].x, ox);   // down: a+o, up: o-a
            float sy = fmaf(sgn, a[r].y, oy);
            a[r].x = fmaf(sx, twx, -(sy * twy));
            a[r].y = fmaf(sx, twy, sy * twx);
        }
        if (half > 1) u = cmul(u, u);
    }
}

static __device__ __constant__ int BR4[16] = {0,8,4,12,2,10,6,14,1,9,5,13,3,11,7,15};

// ---------------- Kernel 1: row FFTs; writes permuted-layout fp16 interm -------------
// interm address for (k,h): k*1024 + (h&63)*16 + (h>>6).
// Block blk owns rows {blk + 64r, r=0..15}; wave w does rows blk+128w, blk+128w+64.
__global__ __launch_bounds__(512) void k_rowfft(const float* __restrict__ x,
                                                __half2* __restrict__ interm,
                                                int img0) {
    __shared__ __half2 tile[WR][17]; // [k][r], +1 pad & XOR swizzle
    const int t = threadIdx.x;
    const int w = t >> 6;
    const int l = t & 63;
    const int blk = blockIdx.x;           // 0..63
    const int iy = blockIdx.y;
    const int img = img0 + iy;
    const int h1 = blk + 128 * w;         // r-index 2w
    const int h2 = h1 + 64;               // r-index 2w+1

    const float* r1 = x + ((size_t)img * HH + h1) * WWID;
    const float* r2 = x + ((size_t)img * HH + h2) * WWID;
    float2 a[16];
#pragma unroll
    for (int j = 0; j < 16; ++j) {
        int i = l + 64 * j;
        a[BR4[j]] = make_float2(r1[i], r2[i]);
    }

    float2 u16 = wave_fft_AB(a, l);
    wave_fft_C(a, l, u16);

    // unpack Z = A + iB -> rfft(A), rfft(B); partner Z[1024-k] at lane p^63, reg 16-r
    const int b = (int)(__brev((unsigned)l) >> 26);
#pragma unroll
    for (int r = 0; r < 16; ++r) {
        float2 znr;
        if (r == 0) {
            int cblk = (64 - b) & 63;
            int q = (int)(__brev((unsigned)cblk) >> 26);
            znr.x = __shfl(a[0].x, q);
            znr.y = __shfl(a[0].y, q);
        } else {
            znr.x = __shfl_xor(a[16 - r].x, 63);
            znr.y = __shfl_xor(a[16 - r].y, 63);
        }
        int k = 16 * b + r;
        if (k <= 512) {
            int cc = b & 15;
            tile[k][(2 * w) ^ cc] =
                __floats2half2_rn(0.5f * (a[r].x + znr.x), 0.5f * (a[r].y - znr.y));
            tile[k][(2 * w + 1) ^ cc] =
                __floats2half2_rn(0.5f * (a[r].y + znr.y), 0.5f * (znr.x - a[r].x));
        }
    }
    __syncthreads();

    // write-out: (k, r) -> k*1024 + blk*16 + r  (64B runs per k)
    __half2* gout = interm + (size_t)iy * WR * 1024 + blk * 16;
    for (int idx = t; idx < WR * 16; idx += 512) {
        int k = idx >> 4;
        int r = idx & 15;
        gout[(size_t)k * 1024 + r] = tile[k][r ^ ((k >> 4) & 15)];
    }
}

// ------------- Kernel 2: column FFTs, register-resident, vectorized loads ------------
__global__ __launch_bounds__(512) void k_colfft(const __half2* __restrict__ interm,
                                                float* __restrict__ partials,
                                                int img0) {
    __shared__ float wsum[8][KSEG][2];
    __shared__ unsigned wmax[8][KSEG];
    const int t = threadIdx.x;
    const int g = blockIdx.x;
    const int iy = blockIdx.y;
    const int img = img0 + iy;
    const int wv = t >> 6;
    const int l = t & 63;
    const int k = g * 8 + wv;

    for (int i = t; i < 8 * KSEG; i += 512) {
        int w = i / KSEG, bb = i - w * KSEG;
        wsum[w][bb][0] = 0.f; wsum[w][bb][1] = 0.f; wmax[w][bb] = 0u;
    }
    __syncthreads();

    if (k <= 512) {   // wave-uniform
        // lane l's 16 elements are contiguous: p = l*16 + j  -> 4x dwordx4
        const uint4* gq = (const uint4*)(interm + ((size_t)iy * WR + k) * 1024 + l * 16);
        union QU { uint4 q[4]; __half2 h[16]; } qu;
        qu.q[0] = gq[0]; qu.q[1] = gq[1]; qu.q[2] = gq[2]; qu.q[3] = gq[3];
        float2 a[16];
#pragma unroll
        for (int j = 0; j < 16; ++j)
            a[BR4[j]] = __half22float2(qu.h[j]);

        float2 u16 = wave_fft_AB(a, l);
        wave_fft_C(a, l, u16);

        // stats: lane's 16 rows contiguous [16b, 16b+15] -> at most 2 bins (verified r3)
        const int b = (int)(__brev((unsigned)l) >> 26);
        const int h0 = 16 * b;
        const float uf = (float)k * (1.0f / 1024.0f);
        const float uu = uf * uf;
        float vf0 = (float)(h0 < 512 ? h0 : h0 - 1024) * (1.0f / 1024.0f);
        float vfF = (float)(h0 + 15 < 512 ? h0 + 15 : h0 + 15 - 1024) * (1.0f / 1024.0f);
        int binF = fast_bin(sqrtf(fmaf(vf0, vf0, uu)));
        int binL = fast_bin(sqrtf(fmaf(vfF, vfF, uu)));
        const int bHi = (binF > binL) ? binF : binL;
        const float Lmid = (0.707106781186547524f * (float)bHi) * 0.0625f;
        const float Lmid2 = Lmid * Lmid;

        float sA1 = 0.f, sA2 = 0.f, mA = 0.f;
        float sB1 = 0.f, sB2 = 0.f, mB = 0.f;
#pragma unroll
        for (int r = 0; r < 16; ++r) {
            int h = h0 + r;
            float vf = (float)(h < 512 ? h : h - 1024) * (1.0f / 1024.0f);
            float s = fmaf(vf, vf, uu);                    // exact rad^2
            float2 z = a[r];
            float p2 = fmaf(z.x, z.x, z.y * z.y);
            float m = sqrtf(p2) * (1.0f / 1024.0f);
            float msq = p2 * (1.0f / 1048576.0f);
            bool c = (s >= Lmid2);                         // bin == bHi
            sA1 += c ? m : 0.f;
            sA2 += c ? msq : 0.f;
            mA = fmaxf(mA, c ? m : 0.f);
            sB1 += c ? 0.f : m;
            sB2 += c ? 0.f : msq;
            mB = fmaxf(mB, c ? 0.f : m);
        }

        atomicAdd(&wsum[wv][bHi][0], sA1);
        atomicAdd(&wsum[wv][bHi][1], sA2);
        atomicMax(&wmax[wv][bHi], __float_as_uint(mA));
        if (bHi > 0) {
            atomicAdd(&wsum[wv][bHi - 1][0], sB1);
            atomicAdd(&wsum[wv][bHi - 1][1], sB2);
            atomicMax(&wmax[wv][bHi - 1], __float_as_uint(mB));
        }
    }
    __syncthreads();

    if (t < KSEG) {
        float aS = 0.f, bS = 0.f, cM = 0.f;
#pragma unroll
        for (int w = 0; w < 8; ++w) {
            aS += wsum[w][t][0];
            bS += wsum[w][t][1];
            cM = fmaxf(cM, __uint_as_float(wmax[w][t]));
        }
        float* dstp = partials + ((size_t)img * NGRP + g) * (KSEG * 3) + t * 3;
        dstp[0] = aS; dstp[1] = bS; dstp[2] = cM;
    }
}

// ---------------- counts (exact reference binning, deterministic) --------------------
__global__ __launch_bounds__(256) void k_counts(unsigned* __restrict__ counts) {
    int cnt[KSEG];
#pragma unroll
    for (int l = 0; l < KSEG; ++l) cnt[l] = 0;
    const int total = HH * WR;
    for (int idx = blockIdx.x * 256 + threadIdx.x; idx < total; idx += gridDim.x * 256) {
        int h = idx / WR;
        int k = idx - h * WR;
        int bin = radial_bin(h, k);
#pragma unroll
        for (int l = 0; l < KSEG; ++l) cnt[l] += (bin == l) ? 1 : 0;
    }
    const int lane = threadIdx.x & 63;
#pragma unroll
    for (int l = 0; l < KSEG; ++l) {
        int c = cnt[l];
        for (int off = 32; off > 0; off >>= 1) c += __shfl_xor(c, off);
        if (lane == 0 && c > 0) atomicAdd(&counts[l], (unsigned)c);
    }
}

// ---------------- Kernel 3: finalize stats + MLP + LayerNorm -------------------------
__global__ __launch_bounds__(256) void k_mlp(const float* __restrict__ partials,
                                             const unsigned* __restrict__ counts,
                                             const float* __restrict__ W1,
                                             const float* __restrict__ b1,
                                             const float* __restrict__ W2,
                                             const float* __restrict__ b2,
                                             const float* __restrict__ gamma,
                                             const float* __restrict__ beta,
                                             float* __restrict__ out) {
    __shared__ float feat[FIN];
    __shared__ float h1s[FEAT];
    __shared__ float red[FEAT];
    const int b = blockIdx.x;
    const int t = threadIdx.x;
    if (t < 48) {
        int c = t / 16;
        int bin = t % 16;
        const float* p = partials + ((size_t)(b * 3 + c) * NGRP) * (KSEG * 3) + bin * 3;
        float s1 = 0.f, s2 = 0.f, mxv = 0.f;
        for (int gg = 0; gg < NGRP; ++gg) {
            s1 += p[gg * (KSEG * 3) + 0];
            s2 += p[gg * (KSEG * 3) + 1];
            mxv = fmaxf(mxv, p[gg * (KSEG * 3) + 2]);
        }
        float cntf = (float)counts[bin];
        float denom = cntf + 1e-8f;
        float mean = s1 / denom;
        float var = (s2 - 2.0f * mean * s1 + cntf * mean * mean) / denom;
        var = fmaxf(var, 0.0f);
        float sd = sqrtf(var);
        mxv = fmaxf(mxv, 0.0f);
        feat[bin * 9 + 0 + c] = mean;
        feat[bin * 9 + 3 + c] = mxv;
        feat[bin * 9 + 6 + c] = sd;
    }
    __syncthreads();

    float acc = b1[t];
    for (int i = 0; i < FIN; ++i) acc += feat[i] * W1[i * FEAT + t];
    acc = (acc >= 0.0f) ? acc : 0.2f * acc;
    h1s[t] = acc;
    __syncthreads();

    float acc2 = b2[t];
    for (int i = 0; i < FEAT; ++i) acc2 += h1s[i] * W2[i * FEAT + t];

    red[t] = acc2;
    __syncthreads();
    for (int off = 128; off > 0; off >>= 1) {
        if (t < off) red[t] += red[t + off];
        __syncthreads();
    }
    float mu = red[0] * (1.0f / 256.0f);
    __syncthreads();
    float dvt = acc2 - mu;
    red[t] = dvt * dvt;
    __syncthreads();
    for (int off = 128; off > 0; off >>= 1) {
        if (t < off) red[t] += red[t + off];
        __syncthreads();
    }
    float va = red[0] * (1.0f / 256.0f);
    out[(size_t)b * FEAT + t] = dvt / sqrtf(va + 1e-5f) * gamma[t] + beta[t];
}

// --------------------------------------------------------------------------------------
extern "C" void kernel_launch(void* const* d_in, const int* in_sizes, int n_in,
                              void* d_out, int out_size, void* d_ws, size_t ws_size,
                              hipStream_t stream) {
    const float* x     = (const float*)d_in[0];
    const float* W1    = (const float*)d_in[1];
    const float* b1    = (const float*)d_in[2];
    const float* W2    = (const float*)d_in[3];
    const float* b2    = (const float*)d_in[4];
    const float* gamma = (const float*)d_in[5];
    const float* beta  = (const float*)d_in[6];
    float* out = (float*)d_out;

    char* ws = (char*)d_ws;
    unsigned* counts = (unsigned*)ws;
    float* partials = (float*)(ws + 256);
    const size_t partialsBytes = (size_t)NIMG * NGRP * KSEG * 3 * sizeof(float);
    const size_t intermOff = (256 + partialsBytes + 255) & ~(size_t)255;
    __half2* interm = (__half2*)(ws + intermOff);
    const size_t perImg = (size_t)WR * 1024 * sizeof(__half2);

    long long avail = (long long)ws_size - (long long)intermOff;
    int chunk = (avail > 0) ? (int)(avail / (long long)perImg) : 0;
    if (chunk > NIMG) chunk = NIMG;
    if (chunk < 1) chunk = 1;

    hipMemsetAsync(counts, 0, KSEG * sizeof(unsigned), stream);
    k_counts<<<dim3(128), dim3(256), 0, stream>>>(counts);

    for (int img0 = 0; img0 < NIMG; img0 += chunk) {
        int n = NIMG - img0;
        if (n > chunk) n = chunk;
        k_rowfft<<<dim3(64, n), dim3(512), 0, stream>>>(x, interm, img0);
        k_colfft<<<dim3(NGRP, n), dim3(512), 0, stream>>>(interm, partials, img0);
    }

    k_mlp<<<dim3(32), dim3(256), 0, stream>>>(partials, counts, W1, b1, W2, b2,
                                              gamma, beta, out);
}

// Round 8
// 447.039 us; speedup vs baseline: 1.4574x; 1.0433x over previous
//
#include <hip/hip_runtime.h>
#include <hip/hip_fp16.h>
#include <math.h>

#define HH    1024
#define WWID  1024
#define WR    513
#define NIMG  96
#define NGRP  65
#define KSEG  17
#define FEAT  256
#define FIN   144

__device__ __forceinline__ float2 cmul(float2 a, float2 b) {
    return make_float2(a.x * b.x - a.y * b.y, a.x * b.y + a.y * b.x);
}

// exact reference binning (16 compares + sqrt) — used by k_counts
__device__ __forceinline__ int radial_bin(int hf, int k) {
    const float maxr = 0.707106781186547524f;
    float v = (float)(hf < 512 ? hf : hf - 1024) * (1.0f / 1024.0f);
    float u = (float)k * (1.0f / 1024.0f);
    float rad = sqrtf(u * u + v * v);
    int bin = 0;
#pragma unroll
    for (int l = 1; l <= 16; ++l) {
        float lower = (maxr * (float)l) * 0.0625f;
        bin += (rad >= lower) ? 1 : 0;
    }
    return bin;
}

// fast bin with exact boundary adjust (validated r6/r7)
__device__ __forceinline__ int fast_bin(float rad) {
    int c = (int)(rad * 22.62741699796952f);
    if (c > 16) c = 16;
    if (c < 16 && rad >= (0.707106781186547524f * (float)(c + 1)) * 0.0625f) c++;
    else if (rad < (0.707106781186547524f * (float)c) * 0.0625f) c--;
    return c;
}

// ---- register-resident 1024-pt FFT per wave (structure verified r3-r7) --------------
// Steps A+B: input a[BR4[j]] = x[l + 64j]; after call a[r] = V[n1=l][k2=r].
// Returns w1^16 for Step C.
__device__ __forceinline__ float2 wave_fft_AB(float2 a[16], int l) {
    constexpr float TW16C[8] = {1.f, 0.9238795325112867f, 0.7071067811865476f,
                                0.3826834323650898f, 0.f, -0.3826834323650898f,
                                -0.7071067811865476f, -0.9238795325112867f};
    constexpr float TW16S[8] = {0.f, -0.3826834323650898f, -0.7071067811865476f,
                                -0.9238795325112867f, -1.f, -0.9238795325112867f,
                                -0.7071067811865476f, -0.3826834323650898f};
#pragma unroll
    for (int m = 2; m <= 16; m <<= 1) {
        const int half = m >> 1;
        const int tstep = 16 / m;
#pragma unroll
        for (int bse = 0; bse < 16; bse += m) {
#pragma unroll
            for (int jj = 0; jj < 8; ++jj) {
                if (jj < half) {
                    float2 w = make_float2(TW16C[jj * tstep], TW16S[jj * tstep]);
                    float2 tv = cmul(a[bse + half + jj], w);
                    float2 u0 = a[bse + jj];
                    a[bse + jj]        = make_float2(u0.x + tv.x, u0.y + tv.y);
                    a[bse + half + jj] = make_float2(u0.x - tv.x, u0.y - tv.y);
                }
            }
        }
    }
    // Step B: HW-trig base twiddle (|ang| <= 0.39 rad, err ~1e-6), two-level products
    float ang = (float)l * (-6.28318530717958647692f / 1024.0f);
    float2 w1 = make_float2(__cosf(ang), __sinf(ang));
    float2 w2 = cmul(w1, w1);
    float2 w3 = cmul(w2, w1);
    float2 w4 = cmul(w2, w2);
    float2 w8 = cmul(w4, w4);
    float2 w12 = cmul(w8, w4);
    a[1] = cmul(a[1], w1);
    a[2] = cmul(a[2], w2);
    a[3] = cmul(a[3], w3);
#pragma unroll
    for (int r = 4; r < 16; ++r) {
        float2 hi = (r >> 2) == 1 ? w4 : ((r >> 2) == 2 ? w8 : w12);
        float2 p = cmul(a[r], hi);
        int lo = r & 3;
        if (lo == 1) p = cmul(p, w1);
        else if (lo == 2) p = cmul(p, w2);
        else if (lo == 3) p = cmul(p, w3);
        a[r] = p;
    }
    return cmul(w8, w8); // w1^16
}

// Step C: 64-pt DIF across lanes, fma-form butterfly + unconditional twiddle.
// Output: lane p, reg r <-> X[16*bitrev6(p) + r].
__device__ __forceinline__ void wave_fft_C(float2 a[16], int l, float2 u) {
#pragma unroll
    for (int half = 32; half >= 1; half >>= 1) {
        const bool up = (l & half) != 0;
        const float sgn = up ? -1.0f : 1.0f;
        const float twx = up ? -u.x : 1.0f;   // down lanes: identity twiddle
        const float twy = up ? -u.y : 0.0f;
#pragma unroll
        for (int r = 0; r < 16; ++r) {
            float ox = __shfl_xor(a[r].x, half);
            float oy = __shfl_xor(a[r].y, half);
            float sx = fmaf(sgn, a[r].x, ox);   // down: a+o, up: o-a
            float sy = fmaf(sgn, a[r].y, oy);
            a[r].x = fmaf(sx, twx, -(sy * twy));
            a[r].y = fmaf(sx, twy, sy * twx);
        }
        if (half > 1) u = cmul(u, u);
    }
}

static __device__ __constant__ int BR4[16] = {0,8,4,12,2,10,6,14,1,9,5,13,3,11,7,15};

// ---------------- Kernel 1: row FFTs; PACKED spectrum, no unpack ---------------------
// Pairing: Z[q] = row q + i*row (q+512), q = 0..511.
// interm layout: [k][perm(q)] with perm(q) = (q&63)*8 + (q>>6)  (1024 x 512 half2).
// Block = 1024 thr = 16 waves; wave w owns q with perm(q) = blk*16 + w, i.e.
// hA = (w&7)*64 + 2*blk + (w>>3), hB = hA + 512.
__global__ __launch_bounds__(1024) void k_rowfft(const float* __restrict__ x,
                                                 __half2* __restrict__ interm,
                                                 int img0) {
    __shared__ __half2 tile[1024][17]; // [k][slot], XOR swizzle on slot
    const int t = threadIdx.x;
    const int w = t >> 6;      // 0..15
    const int l = t & 63;
    const int blk = blockIdx.x;           // 0..31
    const int iy = blockIdx.y;
    const int img = img0 + iy;
    const int hA = ((w & 7) << 6) + 2 * blk + (w >> 3);
    const int hB = hA + 512;

    const float* r1 = x + ((size_t)img * HH + hA) * WWID;
    const float* r2 = x + ((size_t)img * HH + hB) * WWID;
    float2 a[16];
#pragma unroll
    for (int j = 0; j < 16; ++j) {
        int i = l + 64 * j;
        a[BR4[j]] = make_float2(r1[i], r2[i]);
    }

    float2 u16 = wave_fft_AB(a, l);
    wave_fft_C(a, l, u16);

    // reg r at lane l holds Z[k], k = 16*bitrev6(l)+r — store packed, no unpack
    const int b = (int)(__brev((unsigned)l) >> 26);
#pragma unroll
    for (int r = 0; r < 16; ++r) {
        int k = 16 * b + r;
        tile[k][w ^ (b & 15)] = __floats2half2_rn(a[r].x, a[r].y);
    }
    __syncthreads();

    // coalesced write-out: (k, s) -> k*512 + blk*16 + s  (64B runs per k)
    __half2* gout = interm + (size_t)iy * 1024 * 512 + blk * 16;
#pragma unroll
    for (int it = 0; it < 16; ++it) {
        int idx = t + it * 1024;
        int k = idx >> 4;
        int s = idx & 15;
        gout[(size_t)k * 512 + s] = tile[k][s ^ ((k >> 4) & 15)];
    }
}

// ------------- Kernel 2: column FFTs — unpack-on-load from packed Z ------------------
// Column k (wave) loads perm-contiguous Z[.][k] and Z[.][kn], kn = (1024-k)&1023:
// lane l gets 8 pairs (q = l + 64m): A -> reg BR4[m] (row h=l+64m),
// B -> reg BR4[m+8] (row h+512).  Rest identical to r7.
__global__ __launch_bounds__(512) void k_colfft(const __half2* __restrict__ interm,
                                                float* __restrict__ partials,
                                                int img0) {
    __shared__ float wsum[8][KSEG][2];
    __shared__ unsigned wmax[8][KSEG];
    const int t = threadIdx.x;
    const int g = blockIdx.x;
    const int iy = blockIdx.y;
    const int img = img0 + iy;
    const int wv = t >> 6;
    const int l = t & 63;
    const int k = g * 8 + wv;

    for (int i = t; i < 8 * KSEG; i += 512) {
        int w = i / KSEG, bb = i - w * KSEG;
        wsum[w][bb][0] = 0.f; wsum[w][bb][1] = 0.f; wmax[w][bb] = 0u;
    }
    __syncthreads();

    if (k <= 512) {   // wave-uniform
        const int kn = (1024 - k) & 1023;
        const uint4* ps = (const uint4*)(interm + ((size_t)iy * 1024 + k) * 512 + l * 8);
        const uint4* pn = (const uint4*)(interm + ((size_t)iy * 1024 + kn) * 512 + l * 8);
        union QU { uint4 q[2]; __half2 h[8]; } us, un;
        us.q[0] = ps[0]; us.q[1] = ps[1];
        un.q[0] = pn[0]; un.q[1] = pn[1];

        float2 a[16];
#pragma unroll
        for (int m = 0; m < 8; ++m) {
            float2 zs = __half22float2(us.h[m]);
            float2 zn = __half22float2(un.h[m]);
            a[BR4[m]]     = make_float2(0.5f * (zs.x + zn.x), 0.5f * (zs.y - zn.y));
            a[BR4[m + 8]] = make_float2(0.5f * (zs.y + zn.y), 0.5f * (zn.x - zs.x));
        }

        float2 u16 = wave_fft_AB(a, l);
        wave_fft_C(a, l, u16);

        // stats: lane's 16 rows contiguous [16b, 16b+15] -> at most 2 bins (verified r3)
        const int b = (int)(__brev((unsigned)l) >> 26);
        const int h0 = 16 * b;
        const float uf = (float)k * (1.0f / 1024.0f);
        const float uu = uf * uf;
        float vf0 = (float)(h0 < 512 ? h0 : h0 - 1024) * (1.0f / 1024.0f);
        float vfF = (float)(h0 + 15 < 512 ? h0 + 15 : h0 + 15 - 1024) * (1.0f / 1024.0f);
        int binF = fast_bin(sqrtf(fmaf(vf0, vf0, uu)));
        int binL = fast_bin(sqrtf(fmaf(vfF, vfF, uu)));
        const int bHi = (binF > binL) ? binF : binL;
        const float Lmid = (0.707106781186547524f * (float)bHi) * 0.0625f;
        const float Lmid2 = Lmid * Lmid;

        float sA1 = 0.f, sA2 = 0.f, mA = 0.f;
        float sB1 = 0.f, sB2 = 0.f, mB = 0.f;
#pragma unroll
        for (int r = 0; r < 16; ++r) {
            int h = h0 + r;
            float vf = (float)(h < 512 ? h : h - 1024) * (1.0f / 1024.0f);
            float s = fmaf(vf, vf, uu);                    // exact rad^2
            float2 z = a[r];
            float p2 = fmaf(z.x, z.x, z.y * z.y);
            float m = sqrtf(p2) * (1.0f / 1024.0f);
            float msq = p2 * (1.0f / 1048576.0f);
            bool c = (s >= Lmid2);                         // bin == bHi
            sA1 += c ? m : 0.f;
            sA2 += c ? msq : 0.f;
            mA = fmaxf(mA, c ? m : 0.f);
            sB1 += c ? 0.f : m;
            sB2 += c ? 0.f : msq;
            mB = fmaxf(mB, c ? 0.f : m);
        }

        atomicAdd(&wsum[wv][bHi][0], sA1);
        atomicAdd(&wsum[wv][bHi][1], sA2);
        atomicMax(&wmax[wv][bHi], __float_as_uint(mA));
        if (bHi > 0) {
            atomicAdd(&wsum[wv][bHi - 1][0], sB1);
            atomicAdd(&wsum[wv][bHi - 1][1], sB2);
            atomicMax(&wmax[wv][bHi - 1], __float_as_uint(mB));
        }
    }
    __syncthreads();

    if (t < KSEG) {
        float aS = 0.f, bS = 0.f, cM = 0.f;
#pragma unroll
        for (int w = 0; w < 8; ++w) {
            aS += wsum[w][t][0];
            bS += wsum[w][t][1];
            cM = fmaxf(cM, __uint_as_float(wmax[w][t]));
        }
        float* dstp = partials + ((size_t)img * NGRP + g) * (KSEG * 3) + t * 3;
        dstp[0] = aS; dstp[1] = bS; dstp[2] = cM;
    }
}

// ---------------- counts (exact reference binning, deterministic) --------------------
__global__ __launch_bounds__(256) void k_counts(unsigned* __restrict__ counts) {
    int cnt[KSEG];
#pragma unroll
    for (int l = 0; l < KSEG; ++l) cnt[l] = 0;
    const int total = HH * WR;
    for (int idx = blockIdx.x * 256 + threadIdx.x; idx < total; idx += gridDim.x * 256) {
        int h = idx / WR;
        int k = idx - h * WR;
        int bin = radial_bin(h, k);
#pragma unroll
        for (int l = 0; l < KSEG; ++l) cnt[l] += (bin == l) ? 1 : 0;
    }
    const int lane = threadIdx.x & 63;
#pragma unroll
    for (int l = 0; l < KSEG; ++l) {
        int c = cnt[l];
        for (int off = 32; off > 0; off >>= 1) c += __shfl_xor(c, off);
        if (lane == 0 && c > 0) atomicAdd(&counts[l], (unsigned)c);
    }
}

// ---------------- Kernel 3: finalize stats + MLP + LayerNorm -------------------------
__global__ __launch_bounds__(256) void k_mlp(const float* __restrict__ partials,
                                             const unsigned* __restrict__ counts,
                                             const float* __restrict__ W1,
                                             const float* __restrict__ b1,
                                             const float* __restrict__ W2,
                                             const float* __restrict__ b2,
                                             const float* __restrict__ gamma,
                                             const float* __restrict__ beta,
                                             float* __restrict__ out) {
    __shared__ float feat[FIN];
    __shared__ float h1s[FEAT];
    __shared__ float red[FEAT];
    const int b = blockIdx.x;
    const int t = threadIdx.x;
    if (t < 48) {
        int c = t / 16;
        int bin = t % 16;
        const float* p = partials + ((size_t)(b * 3 + c) * NGRP) * (KSEG * 3) + bin * 3;
        float s1 = 0.f, s2 = 0.f, mxv = 0.f;
        for (int gg = 0; gg < NGRP; ++gg) {
            s1 += p[gg * (KSEG * 3) + 0];
            s2 += p[gg * (KSEG * 3) + 1];
            mxv = fmaxf(mxv, p[gg * (KSEG * 3) + 2]);
        }
        float cntf = (float)counts[bin];
        float denom = cntf + 1e-8f;
        float mean = s1 / denom;
        float var = (s2 - 2.0f * mean * s1 + cntf * mean * mean) / denom;
        var = fmaxf(var, 0.0f);
        float sd = sqrtf(var);
        mxv = fmaxf(mxv, 0.0f);
        feat[bin * 9 + 0 + c] = mean;
        feat[bin * 9 + 3 + c] = mxv;
        feat[bin * 9 + 6 + c] = sd;
    }
    __syncthreads();

    float acc = b1[t];
    for (int i = 0; i < FIN; ++i) acc += feat[i] * W1[i * FEAT + t];
    acc = (acc >= 0.0f) ? acc : 0.2f * acc;
    h1s[t] = acc;
    __syncthreads();

    float acc2 = b2[t];
    for (int i = 0; i < FEAT; ++i) acc2 += h1s[i] * W2[i * FEAT + t];

    red[t] = acc2;
    __syncthreads();
    for (int off = 128; off > 0; off >>= 1) {
        if (t < off) red[t] += red[t + off];
        __syncthreads();
    }
    float mu = red[0] * (1.0f / 256.0f);
    __syncthreads();
    float dvt = acc2 - mu;
    red[t] = dvt * dvt;
    __syncthreads();
    for (int off = 128; off > 0; off >>= 1) {
        if (t < off) red[t] += red[t + off];
        __syncthreads();
    }
    float va = red[0] * (1.0f / 256.0f);
    out[(size_t)b * FEAT + t] = dvt / sqrtf(va + 1e-5f) * gamma[t] + beta[t];
}

// --------------------------------------------------------------------------------------
extern "C" void kernel_launch(void* const* d_in, const int* in_sizes, int n_in,
                              void* d_out, int out_size, void* d_ws, size_t ws_size,
                              hipStream_t stream) {
    const float* x     = (const float*)d_in[0];
    const float* W1    = (const float*)d_in[1];
    const float* b1    = (const float*)d_in[2];
    const float* W2    = (const float*)d_in[3];
    const float* b2    = (const float*)d_in[4];
    const float* gamma = (const float*)d_in[5];
    const float* beta  = (const float*)d_in[6];
    float* out = (float*)d_out;

    char* ws = (char*)d_ws;
    unsigned* counts = (unsigned*)ws;
    float* partials = (float*)(ws + 256);
    const size_t partialsBytes = (size_t)NIMG * NGRP * KSEG * 3 * sizeof(float);
    const size_t intermOff = (256 + partialsBytes + 255) & ~(size_t)255;
    __half2* interm = (__half2*)(ws + intermOff);
    const size_t perImg = (size_t)1024 * 512 * sizeof(__half2);

    long long avail = (long long)ws_size - (long long)intermOff;
    int chunk = (avail > 0) ? (int)(avail / (long long)perImg) : 0;
    if (chunk > NIMG) chunk = NIMG;
    if (chunk < 1) chunk = 1;

    hipMemsetAsync(counts, 0, KSEG * sizeof(unsigned), stream);
    k_counts<<<dim3(128), dim3(256), 0, stream>>>(counts);

    for (int img0 = 0; img0 < NIMG; img0 += chunk) {
        int n = NIMG - img0;
        if (n > chunk) n = chunk;
        k_rowfft<<<dim3(32, n), dim3(1024), 0, stream>>>(x, interm, img0);
        k_colfft<<<dim3(NGRP, n), dim3(512), 0, stream>>>(interm, partials, img0);
    }

    k_mlp<<<dim3(32), dim3(256), 0, stream>>>(partials, counts, W1, b1, W2, b2,
                                              gamma, beta, out);
}